// Round 4
// baseline (76.275 us; speedup 1.0000x reference)
//
#include <hip/hip_runtime.h>
#include <math.h>

// KAN layer as pre-fused GEMM (R9 = R8 + halved W re-read traffic).
//   W[i*12+g][o] = sf[i,o]*cp[i,o,g] (g<11),  W[i*12+11][o] = sf[i,o]
//   Feat[b,i*12+g] = basis_g(x[b,i]),  Feat[b,i*12+11] = silu(x[b,i])
// R8 post-mortem: 16 waves/CU == 8 waves/CU in total time -> main is NOT
// latency/occupancy-bound. Remaining unexplained cost: W is read across a
// kernel boundary -> L2-cold -> each block pulls its 192KB W-slice from L3
// (invisible in FETCH_SIZE). 512 blocks x 192KB = 96MB of L3 traffic.
// R9: BT 8->16 (256 blocks, 1/CU) halves that to 48MB; prep rewritten with
// LDS transpose so CP loads and W stores are fully coalesced (128 blocks).

#define IN_DIM   128
#define OUT_DIM  128
#define NCP      11
#define GK       15
#define FS       12            // features per i
#define KTOT     (IN_DIM * FS) // 1536
#define BT       16            // batch rows per block
#define OT       32            // outputs per block
#define VO       4             // outputs per thread
#define KSP      64            // k-split groups: threads = (OT/VO)*KSP = 512
#define NJ       (KTOT / 4 / KSP) // 6 k-groups per thread
#define THREADS  512
#define RPAD     516           // slice stride (mod 32 == 4, R5/R7/R8-proven)

__global__ __launch_bounds__(256)
void kan_prep(const float* __restrict__ CP,   // [128,128,11]
              const float* __restrict__ SF,   // [128,128]
              float* __restrict__ W)          // [1536,128]
{
    // One block per i. CP row (128*11 floats, contiguous) staged through
    // LDS so both the global loads and the W stores are coalesced.
    __shared__ float cpL[IN_DIM * NCP];        // 1408 floats
    __shared__ float sfL[OUT_DIM];

    const int i = blockIdx.x;
    const int t = threadIdx.x;

    const float4* src = (const float4*)(CP + i * OUT_DIM * NCP); // 16B-aligned
    #pragma unroll
    for (int q = t; q < (OUT_DIM * NCP) / 4; q += 256)           // 352 float4
        ((float4*)cpL)[q] = src[q];
    if (t < OUT_DIM) sfL[t] = SF[i * OUT_DIM + t];
    __syncthreads();

    #pragma unroll
    for (int e = t; e < FS * OUT_DIM; e += 256) {                // 1536
        const int g = e >> 7;                  // 0..11
        const int o = e & (OUT_DIM - 1);
        const float s = sfL[o];
        // cpL[o*11+g]: consecutive o -> stride 11 (coprime w/ 32) -> no conflict
        const float w = (g < NCP) ? s * cpL[o * NCP + g] : s;
        W[(i * FS + g) * OUT_DIM + o] = w;     // coalesced 512B per row
    }
}

__global__ __launch_bounds__(THREADS, 2)
void kan_main(const float* __restrict__ X,    // [B,128]
              const float* __restrict__ GR,   // [128,128,15]
              const float* __restrict__ W,    // [1536,128]
              float* __restrict__ OUT)        // [B,128]
{
    // One buffer, two lives: phases 1/2 use the first 96KB as F[BT*KTOT];
    // the reduction reuses it as red[KSP][RPAD]. 129KB/block -> 1 block/CU.
    __shared__ float S[KSP * RPAD];            // 33024 floats = 129 KB

    const int tid = threadIdx.x;
    const int b0  = blockIdx.x * BT;
    const int o0  = blockIdx.y * OT;

    // uniform knots (wave-uniform scalar loads; denominators are d*h)
    const float t0 = GR[0];
    const float h  = GR[1] - t0;
    const float r1 = 1.0f / h;
    const float r2 = 1.0f / (2.0f * h);
    const float r3 = 1.0f / (3.0f * h);
    float kn[GK];
    #pragma unroll
    for (int j = 0; j < GK; ++j) kn[j] = t0 + (float)j * h;

    // ---------------- Phase 1: features into LDS ----------------
    float* F = S;
    #pragma unroll
    for (int kq = 0; kq < (BT * IN_DIM) / THREADS; ++kq) {  // 4
        const int p = tid + kq * THREADS;     // (r,i)
        const int r = p >> 7;
        const int i = p & (IN_DIM - 1);

        const float x = X[(b0 + r) * IN_DIM + i];

        float b[GK - 1];
        #pragma unroll
        for (int j = 0; j < GK - 1; ++j)
            b[j] = (kn[j] <= x && x < kn[j + 1]) ? 1.0f : 0.0f;
        #pragma unroll
        for (int j = 0; j < GK - 2; ++j)
            b[j] = ((x - kn[j]) * b[j] + (kn[j + 2] - x) * b[j + 1]) * r1;
        #pragma unroll
        for (int j = 0; j < GK - 3; ++j)
            b[j] = ((x - kn[j]) * b[j] + (kn[j + 3] - x) * b[j + 1]) * r2;
        #pragma unroll
        for (int j = 0; j < GK - 4; ++j)
            b[j] = ((x - kn[j]) * b[j] + (kn[j + 4] - x) * b[j + 1]) * r3;

        const float silu = x / (1.0f + __expf(-x));

        // 48-byte stride is 16B-aligned -> three b128 stores
        float* f = &F[p * FS];
        *(float4*)(f + 0) = make_float4(b[0], b[1], b[2], b[3]);
        *(float4*)(f + 4) = make_float4(b[4], b[5], b[6], b[7]);
        *(float4*)(f + 8) = make_float4(b[8], b[9], b[10], silu);
    }
    __syncthreads();

    // ---------------- Phase 2: GEMM slice, V=4 outputs/thread ----------
    // thread = (ol in [0,8), ks in [0,64)); k-groups k=4*(ks+64*j).
    // Per group: 4 float4 W loads + 8-lane-broadcast ds_read_b128 F reads
    // (8 distinct addrs/wave spanning all 32 banks) + 16r*16 FMAs.
    const int ol = tid & (OT / VO - 1);        // 0..7
    const int ks = tid >> 3;                   // 0..63
    const int o4 = o0 + VO * ol;

    float acc[BT][VO];
    #pragma unroll
    for (int r = 0; r < BT; ++r)
        #pragma unroll
        for (int v = 0; v < VO; ++v) acc[r][v] = 0.0f;

    #pragma unroll
    for (int j = 0; j < NJ; ++j) {
        const int kg = 4 * (ks + KSP * j);     // multiple of 4

        float4 w0 = *(const float4*)&W[(kg + 0) * OUT_DIM + o4];
        float4 w1 = *(const float4*)&W[(kg + 1) * OUT_DIM + o4];
        float4 w2 = *(const float4*)&W[(kg + 2) * OUT_DIM + o4];
        float4 w3 = *(const float4*)&W[(kg + 3) * OUT_DIM + o4];

        #pragma unroll
        for (int r = 0; r < BT; ++r) {
            const float4 f = *(const float4*)&F[r * KTOT + kg];
            acc[r][0] = fmaf(f.x, w0.x, acc[r][0]);
            acc[r][1] = fmaf(f.x, w0.y, acc[r][1]);
            acc[r][2] = fmaf(f.x, w0.z, acc[r][2]);
            acc[r][3] = fmaf(f.x, w0.w, acc[r][3]);
            acc[r][0] = fmaf(f.y, w1.x, acc[r][0]);
            acc[r][1] = fmaf(f.y, w1.y, acc[r][1]);
            acc[r][2] = fmaf(f.y, w1.z, acc[r][2]);
            acc[r][3] = fmaf(f.y, w1.w, acc[r][3]);
            acc[r][0] = fmaf(f.z, w2.x, acc[r][0]);
            acc[r][1] = fmaf(f.z, w2.y, acc[r][1]);
            acc[r][2] = fmaf(f.z, w2.z, acc[r][2]);
            acc[r][3] = fmaf(f.z, w2.w, acc[r][3]);
            acc[r][0] = fmaf(f.w, w3.x, acc[r][0]);
            acc[r][1] = fmaf(f.w, w3.y, acc[r][1]);
            acc[r][2] = fmaf(f.w, w3.z, acc[r][2]);
            acc[r][3] = fmaf(f.w, w3.w, acc[r][3]);
        }
    }

    // ---------------- reduction over 64 k-slices (reuse S) --------------
    __syncthreads();
    float* red = S;                            // 64*516 floats = 129 KB
    #pragma unroll
    for (int r = 0; r < BT; ++r)
        *(float4*)&red[ks * RPAD + r * OT + VO * ol] =
            make_float4(acc[r][0], acc[r][1], acc[r][2], acc[r][3]);
    __syncthreads();

    {
        const int r  = tid >> 5;               // 0..15
        const int oc = tid & 31;               // 0..31
        float v = 0.0f;
        #pragma unroll
        for (int q = 0; q < KSP; ++q)
            v += red[q * RPAD + r * OT + oc];
        OUT[(b0 + r) * OUT_DIM + o0 + oc] = v; // coalesced 128B per r
    }
}

extern "C" void kernel_launch(void* const* d_in, const int* in_sizes, int n_in,
                              void* d_out, int out_size, void* d_ws, size_t ws_size,
                              hipStream_t stream) {
    const float* x  = (const float*)d_in[0];   // [B,128]
    const float* cp = (const float*)d_in[1];   // [128,128,11]
    const float* sf = (const float*)d_in[2];   // [128,128]
    const float* gr = (const float*)d_in[3];   // [128,128,15]
    float* out = (float*)d_out;
    float* W   = (float*)d_ws;                 // 768 KB scratch

    const int batch = in_sizes[0] / IN_DIM;    // 1024

    kan_prep<<<IN_DIM, 256, 0, stream>>>(cp, sf, W);
    dim3 grid(batch / BT, OUT_DIM / OT);       // (64,4) = 256 blocks
    kan_main<<<grid, THREADS, 0, stream>>>(x, gr, W, out);
}

// Round 5
// 69.628 us; speedup vs baseline: 1.0955x; 1.0955x over previous
//
#include <hip/hip_runtime.h>
#include <math.h>

// KAN layer as pre-fused GEMM (R10 = R5 main + R9 coalesced prep).
//   W[i*12+g][o] = sf[i,o]*cp[i,o,g] (g<11),  W[i*12+11][o] = sf[i,o]
//   Feat[b,i*12+g] = basis_g(x[b,i]),  Feat[b,i*12+11] = silu(x[b,i])
// Session evidence: R6 (fused, unaligned CP loads) +8us; R7 (VGPR cap
// spill) +26us; R8 (16 waves/CU) == R5 -> not latency-bound; R9 (halved
// W re-reads) worse -> not W-BW-bound. The R5 shape is the measured
// optimum; only the coalesced prep (R9) is kept as an improvement.

#define IN_DIM   128
#define OUT_DIM  128
#define NCP      11
#define GK       15
#define FS       12            // features per i
#define KTOT     (IN_DIM * FS) // 1536
#define BT       8             // batch rows per block
#define OT       32            // outputs per block
#define VO       4             // outputs per thread
#define KSP      32            // k-split groups: threads = (OT/VO)*KSP = 256
#define NJ       12            // k-groups per thread: KTOT/4/KSP
#define THREADS  256
#define RPAD     260           // padded row stride for reduction scratch

__global__ __launch_bounds__(256)
void kan_prep(const float* __restrict__ CP,   // [128,128,11]
              const float* __restrict__ SF,   // [128,128]
              float* __restrict__ W)          // [1536,128]
{
    // One block per i. CP row (128*11 floats, contiguous) staged through
    // LDS so both the global loads and the W stores are coalesced.
    __shared__ float cpL[OUT_DIM * NCP];       // 1408 floats
    __shared__ float sfL[OUT_DIM];

    const int i = blockIdx.x;
    const int t = threadIdx.x;

    const float4* src = (const float4*)(CP + i * OUT_DIM * NCP); // 16B-aligned
    #pragma unroll
    for (int q = t; q < (OUT_DIM * NCP) / 4; q += 256)           // 352 float4
        ((float4*)cpL)[q] = src[q];
    if (t < OUT_DIM) sfL[t] = SF[i * OUT_DIM + t];
    __syncthreads();

    #pragma unroll
    for (int e = t; e < FS * OUT_DIM; e += 256) {                // 1536
        const int g = e >> 7;                  // 0..11
        const int o = e & (OUT_DIM - 1);
        const float s = sfL[o];
        // cpL[o*11+g]: consecutive o -> stride 11 (coprime w/ 32) -> no conflict
        const float w = (g < NCP) ? s * cpL[o * NCP + g] : s;
        W[(i * FS + g) * OUT_DIM + o] = w;     // coalesced 512B per row
    }
}

__global__ __launch_bounds__(THREADS, 2)
void kan_main(const float* __restrict__ X,    // [B,128]
              const float* __restrict__ GR,   // [128,128,15]
              const float* __restrict__ W,    // [1536,128]
              float* __restrict__ OUT)        // [B,128]
{
    __shared__ float F[BT * KTOT];             // 48 KiB -> 2 blocks/CU

    const int tid = threadIdx.x;
    const int b0  = blockIdx.x * BT;
    const int o0  = blockIdx.y * OT;

    // uniform knots (wave-uniform scalar loads; denominators are d*h)
    const float t0 = GR[0];
    const float h  = GR[1] - t0;
    const float r1 = 1.0f / h;
    const float r2 = 1.0f / (2.0f * h);
    const float r3 = 1.0f / (3.0f * h);
    float kn[GK];
    #pragma unroll
    for (int j = 0; j < GK; ++j) kn[j] = t0 + (float)j * h;

    // ---------------- Phase 1: features into LDS ----------------
    #pragma unroll
    for (int kq = 0; kq < (BT * IN_DIM) / THREADS; ++kq) {
        const int p = tid + kq * THREADS;     // (r,i)
        const int r = p >> 7;
        const int i = p & (IN_DIM - 1);

        const float x = X[(b0 + r) * IN_DIM + i];

        float b[GK - 1];
        #pragma unroll
        for (int j = 0; j < GK - 1; ++j)
            b[j] = (kn[j] <= x && x < kn[j + 1]) ? 1.0f : 0.0f;
        #pragma unroll
        for (int j = 0; j < GK - 2; ++j)
            b[j] = ((x - kn[j]) * b[j] + (kn[j + 2] - x) * b[j + 1]) * r1;
        #pragma unroll
        for (int j = 0; j < GK - 3; ++j)
            b[j] = ((x - kn[j]) * b[j] + (kn[j + 3] - x) * b[j + 1]) * r2;
        #pragma unroll
        for (int j = 0; j < GK - 4; ++j)
            b[j] = ((x - kn[j]) * b[j] + (kn[j + 4] - x) * b[j + 1]) * r3;

        const float silu = x / (1.0f + __expf(-x));

        // 48-byte stride is 16B-aligned -> three b128 stores
        float* f = &F[p * FS];
        *(float4*)(f + 0) = make_float4(b[0], b[1], b[2], b[3]);
        *(float4*)(f + 4) = make_float4(b[4], b[5], b[6], b[7]);
        *(float4*)(f + 8) = make_float4(b[8], b[9], b[10], silu);
    }
    __syncthreads();

    // ---------------- Phase 2: GEMM slice, V=4 outputs/thread ----------
    // thread = (ol in [0,8), ks in [0,32)); k-groups k=4*(ks+32*j).
    // Per group: 4 float4 W loads + 8 ds_read_b128 F reads + 128 FMAs.
    const int ol = tid & (OT / VO - 1);        // 0..7
    const int ks = tid >> 3;                   // 0..31
    const int o4 = o0 + VO * ol;

    float acc[BT][VO];
    #pragma unroll
    for (int r = 0; r < BT; ++r)
        #pragma unroll
        for (int v = 0; v < VO; ++v) acc[r][v] = 0.0f;

    #pragma unroll
    for (int j = 0; j < NJ; ++j) {
        const int kg = 4 * (ks + KSP * j);     // multiple of 4

        float4 w0 = *(const float4*)&W[(kg + 0) * OUT_DIM + o4];
        float4 w1 = *(const float4*)&W[(kg + 1) * OUT_DIM + o4];
        float4 w2 = *(const float4*)&W[(kg + 2) * OUT_DIM + o4];
        float4 w3 = *(const float4*)&W[(kg + 3) * OUT_DIM + o4];

        #pragma unroll
        for (int r = 0; r < BT; ++r) {
            const float4 f = *(const float4*)&F[r * KTOT + kg];
            acc[r][0] = fmaf(f.x, w0.x, acc[r][0]);
            acc[r][1] = fmaf(f.x, w0.y, acc[r][1]);
            acc[r][2] = fmaf(f.x, w0.z, acc[r][2]);
            acc[r][3] = fmaf(f.x, w0.w, acc[r][3]);
            acc[r][0] = fmaf(f.y, w1.x, acc[r][0]);
            acc[r][1] = fmaf(f.y, w1.y, acc[r][1]);
            acc[r][2] = fmaf(f.y, w1.z, acc[r][2]);
            acc[r][3] = fmaf(f.y, w1.w, acc[r][3]);
            acc[r][0] = fmaf(f.z, w2.x, acc[r][0]);
            acc[r][1] = fmaf(f.z, w2.y, acc[r][1]);
            acc[r][2] = fmaf(f.z, w2.z, acc[r][2]);
            acc[r][3] = fmaf(f.z, w2.w, acc[r][3]);
            acc[r][0] = fmaf(f.w, w3.x, acc[r][0]);
            acc[r][1] = fmaf(f.w, w3.y, acc[r][1]);
            acc[r][2] = fmaf(f.w, w3.z, acc[r][2]);
            acc[r][3] = fmaf(f.w, w3.w, acc[r][3]);
        }
    }

    // ---------------- reduction over 32 k-slices (reuse F) --------------
    __syncthreads();
    float* red = F;                            // 32*RPAD*4 B = 33 KB < 48 KB
    #pragma unroll
    for (int r = 0; r < BT; ++r)
        *(float4*)&red[ks * RPAD + r * OT + VO * ol] =
            make_float4(acc[r][0], acc[r][1], acc[r][2], acc[r][3]);
    __syncthreads();

    {
        const int r  = tid >> 5;               // 0..7
        const int oc = tid & 31;               // 0..31
        float v = 0.0f;
        #pragma unroll
        for (int q = 0; q < KSP; ++q)
            v += red[q * RPAD + r * OT + oc];
        OUT[(b0 + r) * OUT_DIM + o0 + oc] = v; // coalesced 128B per r
    }
}

extern "C" void kernel_launch(void* const* d_in, const int* in_sizes, int n_in,
                              void* d_out, int out_size, void* d_ws, size_t ws_size,
                              hipStream_t stream) {
    const float* x  = (const float*)d_in[0];   // [B,128]
    const float* cp = (const float*)d_in[1];   // [128,128,11]
    const float* sf = (const float*)d_in[2];   // [128,128]
    const float* gr = (const float*)d_in[3];   // [128,128,15]
    float* out = (float*)d_out;
    float* W   = (float*)d_ws;                 // 768 KB scratch

    const int batch = in_sizes[0] / IN_DIM;    // 1024

    kan_prep<<<IN_DIM, 256, 0, stream>>>(cp, sf, W);
    dim3 grid(batch / BT, OUT_DIM / OT);       // (128,4) = 512 blocks
    kan_main<<<grid, THREADS, 0, stream>>>(x, gr, W, out);
}